// Round 7
// baseline (372.035 us; speedup 1.0000x reference)
//
#include <hip/hip_runtime.h>
#include <hip/hip_bf16.h>
#include <math.h>

typedef __bf16 bf16;
typedef __attribute__((ext_vector_type(8))) __bf16 bf16x8;
typedef __attribute__((ext_vector_type(2))) float f32x2;
typedef __attribute__((ext_vector_type(4))) float f32x4;
typedef __attribute__((ext_vector_type(4))) unsigned int uint4v;

#define MFMA16(a, b, c) __builtin_amdgcn_mfma_f32_16x16x32_bf16(a, b, c, 0, 0, 0)

// 1/sqrt(96) * log2(e): folded into Qb so attn scores are already in log2 domain.
#define QSCALE 0.14724450f

__device__ __forceinline__ bf16x8 cvt8v(f32x4 lo, f32x4 hi) {
    bf16x8 r;
    r[0] = (bf16)lo[0]; r[1] = (bf16)lo[1]; r[2] = (bf16)lo[2]; r[3] = (bf16)lo[3];
    r[4] = (bf16)hi[0]; r[5] = (bf16)hi[1]; r[6] = (bf16)hi[2]; r[7] = (bf16)hi[3];
    return r;
}

// Hand-rolled grid barrier (R6 post-mortem: hipLaunchCooperativeKernel never ran —
// NaN graph timing + zeroed output => launch rejected / capture-unsupported).
// 256 blocks with capacity >=2 blocks/CU (LDS 37.9KB, VGPR<=256) are ALWAYS
// co-resident on 256 CUs, so the spin cannot deadlock. Device-scope release/acquire
// handles cross-XCD L2 non-coherence.
__device__ __forceinline__ void grid_barrier(unsigned* bar, int slot, unsigned nblk, int tid) {
    __syncthreads();
    if (tid == 0) {
        __threadfence();
        __hip_atomic_fetch_add(&bar[slot], 1u, __ATOMIC_ACQ_REL, __HIP_MEMORY_SCOPE_AGENT);
        while (__hip_atomic_load(&bar[slot], __ATOMIC_ACQUIRE, __HIP_MEMORY_SCOPE_AGENT) < nblk)
            __builtin_amdgcn_s_sleep(2);
        __threadfence();
    }
    __syncthreads();
}

struct MegaParams {
    const float* W[8];      // fp32 weights (cvt source)
    const float* src[8];    // proj inputs
    const float* B[8];      // biases
    void* dst[8];           // proj outputs
    bf16* Wb;
    const bf16 *Qb, *Kb, *Vb, *Tt, *Vp;
    float* Ctx;
    const float *t, *d, *v, *ln_g, *ln_b;
    float* out;
    unsigned* bar;
};

// ---------------- ONE kernel, 4 phases, 3 atomic grid barriers, 256 blocks ----------------
// Phase 2: c = bid&63 constant per block -> K staged ONCE, V in regs ONCE, reused 16x.
// Phase 3: Plds staged once per 16 row-tiles. Phase 1: R2-exact body, waves loop tiles+=1024.

__global__ __launch_bounds__(256, 2) void mega_kernel(MegaParams P) {
    int tid = threadIdx.x, bid = blockIdx.x;
    int w = tid >> 6, lane = tid & 63;
    int m = lane & 15, quad = lane >> 4;
    unsigned nblk = gridDim.x;

    // LDS union: attn needs 30720 B, cll needs 37888 B.
    __shared__ __align__(16) char smem[37888];
    bf16*  Klds  = (bf16*)smem;                 // [128][104] = 26624 B
    float* wsum4 = (float*)(smem + 26624);      // [4][128]
    float* wk    = (float*)(smem + 28672);      // [128]
    float* ctxp  = (float*)(smem + 29184);      // [4][96]
    char*  pb    = smem;                        // cll Plds, swizzled, 37632 B
    float* red   = (float*)(smem + 37632);      // [16][4]

    // ---- Phase 0: weights fp32 -> bf16 (98304 f32x4 over 256 blocks, 384 each) ----
    {
        int base = bid * 384;
        for (int k = tid; k < 384; k += 256) {
            int e4  = base + k;
            int j   = e4 / 12288;
            int off = (e4 - j * 12288) * 4;
            f32x4 val = *(const f32x4*)(P.W[j] + off);
            bf16* dst = P.Wb + j * 49152 + off;
            dst[0] = (bf16)val[0]; dst[1] = (bf16)val[1];
            dst[2] = (bf16)val[2]; dst[3] = (bf16)val[3];
        }
    }
    grid_barrier(P.bar, 0, nblk, tid);

    // ---- Phase 1: projections (R2-exact per-tile body; 1422 tiles over 1024 waves) ----
    for (int tile = bid * 4 + w; tile < 1422; tile += 1024) {
        int job, t0;
        if      (tile < 256)  { job = 3; t0 = tile; }
        else if (tile < 512)  { job = 4; t0 = tile - 256; }
        else if (tile < 768)  { job = 5; t0 = tile - 512; }
        else if (tile < 1024) { job = 6; t0 = tile - 768; }
        else if (tile < 1416) { job = 7; t0 = tile - 1024; }
        else                  { int r = tile - 1416; job = r >> 1; t0 = r & 1; }
        int r0 = t0 << 5;
        const float* X = P.src[job] + (size_t)(r0 + m) * 512 + quad * 8;
        const bf16*  W = P.Wb + job * 49152 + (size_t)m * 512 + quad * 8;

        f32x4 acc[2][6] = {};
        #pragma unroll
        for (int kk = 0; kk < 512; kk += 32) {
            bf16x8 a0 = cvt8v(*(const f32x4*)(X + kk),
                              *(const f32x4*)(X + kk + 4));
            bf16x8 a1 = cvt8v(*(const f32x4*)(X + 16 * 512 + kk),
                              *(const f32x4*)(X + 16 * 512 + kk + 4));
            #pragma unroll
            for (int nt = 0; nt < 6; nt++) {
                bf16x8 b = *(const bf16x8*)(W + (size_t)nt * 16 * 512 + kk);
                acc[0][nt] = MFMA16(a0, b, acc[0][nt]);
                acc[1][nt] = MFMA16(a1, b, acc[1][nt]);
            }
        }
        bool  norm  = (job < 3) || (job >= 6);
        float scale = (job == 3) ? QSCALE : 1.0f;
        const float* Bv = P.B[job];
        float bb[6];
        #pragma unroll
        for (int nt = 0; nt < 6; nt++) bb[nt] = Bv[nt * 16 + m];
        #pragma unroll
        for (int rt = 0; rt < 2; rt++)
            #pragma unroll
            for (int nt = 0; nt < 6; nt++)
                #pragma unroll
                for (int r = 0; r < 4; r++)
                    acc[rt][nt][r] = (acc[rt][nt][r] + bb[nt]) * scale;
        if (norm) {
            #pragma unroll
            for (int rt = 0; rt < 2; rt++)
                #pragma unroll
                for (int r = 0; r < 4; r++) {
                    float s = 0.0f;
                    #pragma unroll
                    for (int nt = 0; nt < 6; nt++) s += acc[rt][nt][r] * acc[rt][nt][r];
                    s += __shfl_xor(s, 1); s += __shfl_xor(s, 2);
                    s += __shfl_xor(s, 4); s += __shfl_xor(s, 8);
                    float inv = 1.0f / fmaxf(sqrtf(s), 1e-6f);
                    #pragma unroll
                    for (int nt = 0; nt < 6; nt++) acc[rt][nt][r] *= inv;
                }
        }
        if (job < 3) {
            float* dst = (float*)P.dst[job];
            #pragma unroll
            for (int rt = 0; rt < 2; rt++)
                #pragma unroll
                for (int r = 0; r < 4; r++)
                    #pragma unroll
                    for (int nt = 0; nt < 6; nt++)
                        dst[(size_t)(r0 + rt * 16 + quad * 4 + r) * 96 + nt * 16 + m] = acc[rt][nt][r];
        } else {
            bf16* dst = (bf16*)P.dst[job];
            #pragma unroll
            for (int rt = 0; rt < 2; rt++)
                #pragma unroll
                for (int r = 0; r < 4; r++)
                    #pragma unroll
                    for (int nt = 0; nt < 6; nt++)
                        dst[(size_t)(r0 + rt * 16 + quad * 4 + r) * 96 + nt * 16 + m] = (bf16)acc[rt][nt][r];
        }
    }
    grid_barrier(P.bar, 1, nblk, tid);

    // ---- Phase 2: attention. c = bid&63 constant -> stage K once, V in regs once; 16 b's ----
    {
        int c = bid & 63;
        const bf16* K = P.Kb + (size_t)c * (128 * 96);
        const bf16* V = P.Vb + (size_t)c * (128 * 96);
        #pragma unroll
        for (int it = 0; it < 6; it++) {
            int ch = it * 256 + tid;
            int row = ch / 12, seg = ch - row * 12;
            *(uint4v*)(Klds + row * 104 + seg * 8) = *(const uint4v*)(K + ch * 8);
        }
        unsigned vr[32];
        if (lane < 48) {
            #pragma unroll
            for (int r = 0; r < 32; r++)
                vr[r] = *(const unsigned*)(V + (size_t)(w * 32 + r) * 96 + lane * 2);
        }
        __syncthreads();

        for (int i = 0; i < 16; i++) {
            int b = (bid >> 6) + 4 * i;
            int pr = b * 64 + c;
            const bf16* Q = P.Qb + (size_t)b * (128 * 96);

            f32x4 acc[2][8] = {};
            #pragma unroll
            for (int kk = 0; kk < 96; kk += 32) {
                bf16x8 a0 = *(const bf16x8*)(Q + (size_t)(w * 32 + m) * 96 + kk + quad * 8);
                bf16x8 a1 = *(const bf16x8*)(Q + (size_t)(w * 32 + 16 + m) * 96 + kk + quad * 8);
                #pragma unroll
                for (int nt = 0; nt < 8; nt++) {
                    bf16x8 bbk = *(const bf16x8*)(Klds + (nt * 16 + m) * 104 + kk + quad * 8);
                    acc[0][nt] = MFMA16(a0, bbk, acc[0][nt]);
                    acc[1][nt] = MFMA16(a1, bbk, acc[1][nt]);
                }
            }
            float wpart[8];
            #pragma unroll
            for (int nt = 0; nt < 8; nt++) wpart[nt] = 0.0f;
            #pragma unroll
            for (int mt = 0; mt < 2; mt++) {
                #pragma unroll
                for (int r = 0; r < 4; r++) {
                    float tv[8]; float s = 0.0f;
                    #pragma unroll
                    for (int nt = 0; nt < 8; nt++) { tv[nt] = exp2f(acc[mt][nt][r]); s += tv[nt]; }
                    s += __shfl_xor(s, 1); s += __shfl_xor(s, 2);
                    s += __shfl_xor(s, 4); s += __shfl_xor(s, 8);
                    float inv = 1.0f / s;
                    #pragma unroll
                    for (int nt = 0; nt < 8; nt++) wpart[nt] += tv[nt] * inv;
                }
            }
            #pragma unroll
            for (int nt = 0; nt < 8; nt++) {
                wpart[nt] += __shfl_xor(wpart[nt], 16);
                wpart[nt] += __shfl_xor(wpart[nt], 32);
            }
            if (lane < 16) {
                #pragma unroll
                for (int nt = 0; nt < 8; nt++) wsum4[w * 128 + nt * 16 + lane] = wpart[nt];
            }
            __syncthreads();
            if (tid < 128)
                wk[tid] = wsum4[tid] + wsum4[128 + tid] + wsum4[256 + tid] + wsum4[384 + tid];
            __syncthreads();
            if (lane < 48) {
                float c0 = 0.0f, c1 = 0.0f;
                #pragma unroll
                for (int r = 0; r < 32; r++) {
                    unsigned u = vr[r];
                    float wkk = wk[w * 32 + r];
                    c0 += wkk * __uint_as_float(u << 16);
                    c1 += wkk * __uint_as_float(u & 0xffff0000u);
                }
                ctxp[w * 96 + lane * 2]     = c0;
                ctxp[w * 96 + lane * 2 + 1] = c1;
            }
            __syncthreads();
            if (tid < 96)
                P.Ctx[(size_t)pr * 96 + tid] =
                    (ctxp[tid] + ctxp[96 + tid] + ctxp[192 + tid] + ctxp[288 + tid]) * (1.0f / 128.0f);
            __syncthreads();
        }
    }
    grid_barrier(P.bar, 2, nblk, tid);

    // ---- Phase 3: CLL + fused epilogue. c = bid>>2, 16 row-tiles per block ----
    {
        int c = bid >> 2, bg2 = bid & 3;
        const bf16* Pv = P.Vp + (size_t)c * (196 * 96);
        for (int ch = tid; ch < 2352; ch += 256) {
            int row = ch / 12, seg = ch - row * 12;
            int addr = (row * 192 + seg * 16) ^ ((row & 7) << 4);
            *(uint4v*)(pb + addr) = *(const uint4v*)(Pv + ch * 8);
        }
        int rofs[13], rx[13];
        #pragma unroll
        for (int nt = 0; nt < 13; nt++) {
            int r = nt * 16 + m; if (r > 195) r = 195;
            rofs[nt] = r * 192 + quad * 16;
            rx[nt]   = (r & 7) << 4;
        }
        __syncthreads();

        for (int bi = 0; bi < 16; bi++) {
            const bf16* T = P.Tt + (size_t)(bg2 * 16 + bi) * (128 * 96);
            f32x4 acc[2][13] = {};
            #pragma unroll
            for (int kk = 0; kk < 96; kk += 32) {
                bf16x8 a0 = *(const bf16x8*)(T + (size_t)(w * 32 + m) * 96 + kk + quad * 8);
                bf16x8 a1 = *(const bf16x8*)(T + (size_t)(w * 32 + 16 + m) * 96 + kk + quad * 8);
                #pragma unroll
                for (int nt = 0; nt < 13; nt++) {
                    bf16x8 bbp = *(const bf16x8*)(pb + ((rofs[nt] + kk * 2) ^ rx[nt]));
                    acc[0][nt] = MFMA16(a0, bbp, acc[0][nt]);
                    acc[1][nt] = MFMA16(a1, bbp, acc[1][nt]);
                }
            }
            float mx = -3.4e38f;
            #pragma unroll
            for (int mt = 0; mt < 2; mt++)
                #pragma unroll
                for (int nt = 0; nt < 13; nt++)
                    #pragma unroll
                    for (int r = 0; r < 4; r++) mx = fmaxf(mx, acc[mt][nt][r]);
            #pragma unroll
            for (int dd = 1; dd < 64; dd <<= 1) mx = fmaxf(mx, __shfl_xor(mx, dd));
            if (lane == 0) red[bi * 4 + w] = mx;
        }
        __syncthreads();

        #pragma unroll
        for (int half = 0; half < 4; half++) {
            int bi = w + half * 4;          // [0,16)
            int i  = bg2 * 16 + bi;         // b row
            int pr = i * 64 + c;
            float scll = fmaxf(fmaxf(red[bi * 4 + 0], red[bi * 4 + 1]),
                               fmaxf(red[bi * 4 + 2], red[bi * 4 + 3]));
            bool act = lane < 48;
            float c0 = 0, c1 = 0, t0 = 0, t1 = 0;
            float dj0 = 0, dj1 = 0, di0 = 0, di1 = 0, v0 = 0, v1 = 0, g0 = 0, g1 = 0, bb0 = 0, bb1 = 0;
            if (act) {
                f32x2 cc  = *(const f32x2*)(P.Ctx + (size_t)pr * 96 + lane * 2);
                f32x2 tt  = *(const f32x2*)(P.t + i * 96 + lane * 2);
                f32x2 ddj = *(const f32x2*)(P.d + c * 96 + lane * 2);
                f32x2 ddi = *(const f32x2*)(P.d + i * 96 + lane * 2);
                f32x2 vv  = *(const f32x2*)(P.v + c * 96 + lane * 2);
                f32x2 gg  = *(const f32x2*)(P.ln_g + lane * 2);
                f32x2 bbv = *(const f32x2*)(P.ln_b + lane * 2);
                c0 = cc[0]; c1 = cc[1]; t0 = tt[0]; t1 = tt[1];
                dj0 = ddj[0]; dj1 = ddj[1]; di0 = ddi[0]; di1 = ddi[1];
                v0 = vv[0]; v1 = vv[1];
                g0 = gg[0]; g1 = gg[1]; bb0 = bbv[0]; bb1 = bbv[1];
            }
            float s = c0 + c1;
            #pragma unroll
            for (int k = 1; k < 64; k <<= 1) s += __shfl_xor(s, k);
            float mean = s * (1.0f / 96.0f);
            float e0 = act ? (c0 - mean) : 0.0f;
            float e1 = act ? (c1 - mean) : 0.0f;
            float q = e0 * e0 + e1 * e1;
            #pragma unroll
            for (int k = 1; k < 64; k <<= 1) q += __shfl_xor(q, k);
            float rstd = rsqrtf(q * (1.0f / 96.0f) + 1e-5f);
            float y0 = act ? (e0 * rstd * g0 + bb0) : 0.0f;
            float y1 = act ? (e1 * rstd * g1 + bb1) : 0.0f;
            float dot = y0 * di0 + y1 * di1;   // S_TGL uses d_i
            float ssq = y0 * y0 + y1 * y1;
            float tg  = t0 * dj0 + t1 * dj1;   // S_TGG uses d_j
            float cg  = t0 * v0 + t1 * v1;
            #pragma unroll
            for (int k = 1; k < 64; k <<= 1) {
                dot += __shfl_xor(dot, k); ssq += __shfl_xor(ssq, k);
                tg  += __shfl_xor(tg, k);  cg  += __shfl_xor(cg, k);
            }
            if (lane == 0) {
                float stgl = dot / fmaxf(sqrtf(ssq), 1e-6f);
                P.out[pr] = 0.5f * (tg + stgl) + 0.5f * (cg + scll);
            }
        }
    }
}

// ---------------- launch ----------------

extern "C" void kernel_launch(void* const* d_in, const int* in_sizes, int n_in,
                              void* d_out, int out_size, void* d_ws, size_t ws_size,
                              hipStream_t stream)
{
    (void)in_sizes; (void)n_in; (void)out_size; (void)ws_size;
    char* ws = (char*)d_ws;
    float* t   = (float*)(ws + 0);                 // 64*96 f32
    float* d   = (float*)(ws + 24576);
    float* v   = (float*)(ws + 49152);
    unsigned* bar = (unsigned*)(ws + 73728);       // 4 u32 barrier counters (gap before Wb)
    bf16* Wb = (bf16*)(ws + 106496);               // 8*96*512 bf16
    bf16* Qb = (bf16*)(ws + 892928);               // 8192*96 bf16
    bf16* Kb = (bf16*)(ws + 892928 + 1572864);
    bf16* Vb = (bf16*)(ws + 892928 + 2 * 1572864);
    bf16* Tt = (bf16*)(ws + 892928 + 3 * 1572864);
    bf16* Vp = (bf16*)(ws + 892928 + 4 * 1572864);         // 12544*96 bf16
    float* Ctx = (float*)(ws + 892928 + 4 * 1572864 + 2408448); // 4096*96 f32

    MegaParams P;
    P.W[0] = (const float*)d_in[6];   // W_t_cls
    P.W[1] = (const float*)d_in[8];   // W_d_cls
    P.W[2] = (const float*)d_in[10];  // W_v_cls
    P.W[3] = (const float*)d_in[16];  // W_tgl_q
    P.W[4] = (const float*)d_in[18];  // W_tgl_k
    P.W[5] = (const float*)d_in[20];  // W_tgl_v
    P.W[6] = (const float*)d_in[12];  // W_t_tok
    P.W[7] = (const float*)d_in[14];  // W_v_patch
    P.src[0] = (const float*)d_in[2];  P.B[0] = (const float*)d_in[7];  P.dst[0] = t;   // t_cls
    P.src[1] = (const float*)d_in[0];  P.B[1] = (const float*)d_in[9];  P.dst[1] = d;   // d_cls
    P.src[2] = (const float*)d_in[4];  P.B[2] = (const float*)d_in[11]; P.dst[2] = v;   // v_cls
    P.src[3] = (const float*)d_in[1];  P.B[3] = (const float*)d_in[17]; P.dst[3] = Qb;  // Q (scaled)
    P.src[4] = (const float*)d_in[3];  P.B[4] = (const float*)d_in[19]; P.dst[4] = Kb;  // K
    P.src[5] = (const float*)d_in[3];  P.B[5] = (const float*)d_in[21]; P.dst[5] = Vb;  // V
    P.src[6] = (const float*)d_in[3];  P.B[6] = (const float*)d_in[13]; P.dst[6] = Tt;  // t_tok
    P.src[7] = (const float*)d_in[5];  P.B[7] = (const float*)d_in[15]; P.dst[7] = Vp;  // v_patch
    P.Wb = Wb;
    P.Qb = Qb; P.Kb = Kb; P.Vb = Vb; P.Tt = Tt; P.Vp = Vp;
    P.Ctx = Ctx;
    P.t = t; P.d = d; P.v = v;
    P.ln_g = (const float*)d_in[22];
    P.ln_b = (const float*)d_in[23];
    P.out = (float*)d_out;
    P.bar = bar;

    hipMemsetAsync(bar, 0, 16, stream);
    hipLaunchKernelGGL(mega_kernel, dim3(256), dim3(256), 0, stream, P);
}

// Round 9
// 238.408 us; speedup vs baseline: 1.5605x; 1.5605x over previous
//
#include <hip/hip_runtime.h>
#include <hip/hip_bf16.h>
#include <math.h>

typedef __bf16 bf16;
typedef __attribute__((ext_vector_type(8))) __bf16 bf16x8;
typedef __attribute__((ext_vector_type(2))) float f32x2;
typedef __attribute__((ext_vector_type(4))) float f32x4;
typedef __attribute__((ext_vector_type(4))) unsigned int uint4v;

#define MFMA16(a, b, c) __builtin_amdgcn_mfma_f32_16x16x32_bf16(a, b, c, 0, 0, 0)

// 1/sqrt(96) * log2(e): folded into Qb so attn scores are already in log2 domain.
#define QSCALE 0.14724450f

__device__ __forceinline__ bf16x8 cvt8v(f32x4 lo, f32x4 hi) {
    bf16x8 r;
    r[0] = (bf16)lo[0]; r[1] = (bf16)lo[1]; r[2] = (bf16)lo[2]; r[3] = (bf16)lo[3];
    r[4] = (bf16)hi[0]; r[5] = (bf16)hi[1]; r[6] = (bf16)hi[2]; r[7] = (bf16)hi[3];
    return r;
}

// ---------------- Kernel 0: convert all 8 weight matrices fp32 -> bf16 ----------------

struct WPtrs { const float* W[8]; };

__global__ __launch_bounds__(256) void cvtw_kernel(WPtrs wp, bf16* __restrict__ Wb) {
    int j   = blockIdx.x / 48;
    int blk = blockIdx.x - j * 48;
    int idx = (blk * 256 + threadIdx.x) * 4;
    f32x4 v = *(const f32x4*)(wp.W[j] + idx);
    bf16* dst = Wb + j * 49152 + idx;
    dst[0] = (bf16)v[0]; dst[1] = (bf16)v[1]; dst[2] = (bf16)v[2]; dst[3] = (bf16)v[3];
}

// ---------------- Kernel 1: projections — pipelined register GEMM ----------------
// R7 model: proj time ~ total load instructions x ~125cy/load/CU -> per-wave loads are
// SERIAL (MLP 2-3, VGPR 56-64). R8 single change: explicit 2x4-iter software pipeline.
// 32 A-loads live before first consume (128 VGPR), batch n+1 issued during batch n's
// MFMAs; launch_bounds(256,1) lifts the register cap. Everything else R2-exact.
// (R8 bench was an infra failure — container acquisition — so this is a clean resubmit.)

struct ProjParams {
    const float* src[8];
    const float* B[8];
    void* dst[8];
    const bf16* Wb;
};

// wave-id map: [0,256) Q, [256,512) K, [512,768) V, [768,1024) t_tok,
// [1024,1416) v_patch, [1416,1422) cls (2 tiles each of t/d/v_cls).
__global__ __launch_bounds__(256, 1) void proj_kernel(ProjParams p) {
    int w = threadIdx.x >> 6, lane = threadIdx.x & 63;
    int gw = blockIdx.x * 4 + w;
    int m = lane & 15, quad = lane >> 4;

    int job, t0;
    if      (gw < 256)  { job = 3; t0 = gw; }
    else if (gw < 512)  { job = 4; t0 = gw - 256; }
    else if (gw < 768)  { job = 5; t0 = gw - 512; }
    else if (gw < 1024) { job = 6; t0 = gw - 768; }
    else if (gw < 1416) { job = 7; t0 = gw - 1024; }
    else if (gw < 1422) { int r = gw - 1416; job = r >> 1; t0 = r & 1; }
    else return;
    int r0 = t0 << 5;

    const float* X = p.src[job] + (size_t)(r0 + m) * 512 + quad * 8;
    const bf16*  W = p.Wb + job * 49152 + (size_t)m * 512 + quad * 8;

    f32x4 acc[2][6] = {};
    f32x4 pa[4][4], pb[4][4];

#define LOADB(arr, base) \
    { _Pragma("unroll") for (int it = 0; it < 4; it++) { \
        arr[it][0] = *(const f32x4*)(X + (base) + it * 32); \
        arr[it][1] = *(const f32x4*)(X + (base) + it * 32 + 4); \
        arr[it][2] = *(const f32x4*)(X + 8192 + (base) + it * 32); \
        arr[it][3] = *(const f32x4*)(X + 8192 + (base) + it * 32 + 4); } }

#define DOB(arr, base) \
    { _Pragma("unroll") for (int it = 0; it < 4; it++) { \
        bf16x8 a0 = cvt8v(arr[it][0], arr[it][1]); \
        bf16x8 a1 = cvt8v(arr[it][2], arr[it][3]); \
        _Pragma("unroll") for (int nt = 0; nt < 6; nt++) { \
            bf16x8 bw = *(const bf16x8*)(W + (size_t)nt * 8192 + (base) + it * 32); \
            acc[0][nt] = MFMA16(a0, bw, acc[0][nt]); \
            acc[1][nt] = MFMA16(a1, bw, acc[1][nt]); } } }

    LOADB(pa, 0)        // 16 loads in flight
    LOADB(pb, 128)      // 32 loads in flight before first consume
    DOB(pa, 0)
    LOADB(pa, 256)      // refill while pb still pending
    DOB(pb, 128)
    LOADB(pb, 384)
    DOB(pa, 256)
    DOB(pb, 384)
#undef LOADB
#undef DOB

    // epilogue: bias (+scale), optional intra-wave l2-norm, store. (R2-exact)
    bool  norm  = (job < 3) || (job >= 6);
    float scale = (job == 3) ? QSCALE : 1.0f;
    const float* Bv = p.B[job];
    float bb[6];
    #pragma unroll
    for (int nt = 0; nt < 6; nt++) bb[nt] = Bv[nt * 16 + m];

    #pragma unroll
    for (int rt = 0; rt < 2; rt++)
        #pragma unroll
        for (int nt = 0; nt < 6; nt++)
            #pragma unroll
            for (int r = 0; r < 4; r++)
                acc[rt][nt][r] = (acc[rt][nt][r] + bb[nt]) * scale;

    if (norm) {
        #pragma unroll
        for (int rt = 0; rt < 2; rt++)
            #pragma unroll
            for (int r = 0; r < 4; r++) {
                float s = 0.0f;
                #pragma unroll
                for (int nt = 0; nt < 6; nt++) s += acc[rt][nt][r] * acc[rt][nt][r];
                s += __shfl_xor(s, 1); s += __shfl_xor(s, 2);
                s += __shfl_xor(s, 4); s += __shfl_xor(s, 8);
                float inv = 1.0f / fmaxf(sqrtf(s), 1e-6f);
                #pragma unroll
                for (int nt = 0; nt < 6; nt++) acc[rt][nt][r] *= inv;
            }
    }

    if (job < 3) {
        float* dst = (float*)p.dst[job];
        #pragma unroll
        for (int rt = 0; rt < 2; rt++)
            #pragma unroll
            for (int r = 0; r < 4; r++)
                #pragma unroll
                for (int nt = 0; nt < 6; nt++)
                    dst[(size_t)(r0 + rt * 16 + quad * 4 + r) * 96 + nt * 16 + m] = acc[rt][nt][r];
    } else {
        bf16* dst = (bf16*)p.dst[job];
        #pragma unroll
        for (int rt = 0; rt < 2; rt++)
            #pragma unroll
            for (int r = 0; r < 4; r++)
                #pragma unroll
                for (int nt = 0; nt < 6; nt++)
                    dst[(size_t)(r0 + rt * 16 + quad * 4 + r) * 96 + nt * 16 + m] = (bf16)acc[rt][nt][r];
    }
}

// ---------------- Kernel 2: TGL attention per (b,c) pair -> ctx[96] ----------------
// EXACT R2 form — best measured (53.8us). Padded Klds, V-tail from global after wk,
// full-precision softmax divide. (R3's swizzle+V-preload variant measured 59.2: the
// V-preload's +16 VGPR cut occupancy 28->19.5% — net loss at free-floating occupancy.)

__global__ __launch_bounds__(256) void attn_kernel(
    const bf16* __restrict__ Qg, const bf16* __restrict__ Kg, const bf16* __restrict__ Vg,
    float* __restrict__ Ctx)
{
    int pr = blockIdx.x;
    int b = pr >> 6, c = pr & 63;
    int tid = threadIdx.x, lane = tid & 63, w = tid >> 6;
    int m = lane & 15, quad = lane >> 4;
    const bf16* Q = Qg + (size_t)b * (128 * 96);
    const bf16* K = Kg + (size_t)c * (128 * 96);
    const bf16* V = Vg + (size_t)c * (128 * 96);

    __shared__ __align__(16) bf16 Klds[128 * 104];
    #pragma unroll
    for (int it = 0; it < 6; it++) {
        int ch = it * 256 + tid;
        int row = ch / 12, seg = ch - row * 12;
        *(uint4v*)(Klds + row * 104 + seg * 8) = *(const uint4v*)(K + ch * 8);
    }
    __syncthreads();

    f32x4 acc[2][8] = {};
    #pragma unroll
    for (int kk = 0; kk < 96; kk += 32) {
        bf16x8 a0 = *(const bf16x8*)(Q + (size_t)(w * 32 + m) * 96 + kk + quad * 8);
        bf16x8 a1 = *(const bf16x8*)(Q + (size_t)(w * 32 + 16 + m) * 96 + kk + quad * 8);
        #pragma unroll
        for (int nt = 0; nt < 8; nt++) {
            bf16x8 bb = *(const bf16x8*)(Klds + (nt * 16 + m) * 104 + kk + quad * 8);
            acc[0][nt] = MFMA16(a0, bb, acc[0][nt]);
            acc[1][nt] = MFMA16(a1, bb, acc[1][nt]);
        }
    }
    float wpart[8];
    #pragma unroll
    for (int nt = 0; nt < 8; nt++) wpart[nt] = 0.0f;
    #pragma unroll
    for (int mt = 0; mt < 2; mt++) {
        #pragma unroll
        for (int r = 0; r < 4; r++) {
            float tv[8]; float s = 0.0f;
            #pragma unroll
            for (int nt = 0; nt < 8; nt++) { tv[nt] = exp2f(acc[mt][nt][r]); s += tv[nt]; }
            s += __shfl_xor(s, 1); s += __shfl_xor(s, 2);
            s += __shfl_xor(s, 4); s += __shfl_xor(s, 8);
            float inv = 1.0f / s;
            #pragma unroll
            for (int nt = 0; nt < 8; nt++) wpart[nt] += tv[nt] * inv;
        }
    }
    #pragma unroll
    for (int nt = 0; nt < 8; nt++) {
        wpart[nt] += __shfl_xor(wpart[nt], 16);
        wpart[nt] += __shfl_xor(wpart[nt], 32);
    }
    __shared__ float wsum4[4][128];
    __shared__ float wk[128];
    __shared__ float ctxp[4][96];
    if (lane < 16) {
        #pragma unroll
        for (int nt = 0; nt < 8; nt++) wsum4[w][nt * 16 + lane] = wpart[nt];
    }
    __syncthreads();
    if (tid < 128) wk[tid] = wsum4[0][tid] + wsum4[1][tid] + wsum4[2][tid] + wsum4[3][tid];
    __syncthreads();
    {
        float c0 = 0.0f, c1 = 0.0f;
        if (lane < 48) {
            #pragma unroll 4
            for (int r = 0; r < 32; r++) {
                int k = w * 32 + r;
                unsigned u = *(const unsigned*)(V + (size_t)k * 96 + lane * 2);
                float lo = __uint_as_float(u << 16);
                float hi = __uint_as_float(u & 0xffff0000u);
                float wkk = wk[k];
                c0 += wkk * lo; c1 += wkk * hi;
            }
            ctxp[w][lane * 2]     = c0;
            ctxp[w][lane * 2 + 1] = c1;
        }
    }
    __syncthreads();
    if (tid < 96)
        Ctx[(size_t)pr * 96 + tid] =
            (ctxp[0][tid] + ctxp[1][tid] + ctxp[2][tid] + ctxp[3][tid]) * (1.0f / 128.0f);
}

// ---------------- Kernel 3: CLL + fused epilogue (R5 form: swizzled Plds) ----------------

__global__ __launch_bounds__(256) void cll_kernel(
    const bf16* __restrict__ Tt, const bf16* __restrict__ Vp,
    const float* __restrict__ Ctx, const float* __restrict__ t,
    const float* __restrict__ d, const float* __restrict__ v,
    const float* __restrict__ ln_g, const float* __restrict__ ln_b,
    float* __restrict__ out)
{
    int c = blockIdx.x >> 3, bg = blockIdx.x & 7;
    int tid = threadIdx.x, lane = tid & 63, w = tid >> 6;
    int m = lane & 15, quad = lane >> 4;
    const bf16* P = Vp + (size_t)c * (196 * 96);

    __shared__ __align__(16) bf16 Plds[196 * 96];
    __shared__ float red[8][4];
    char* pb = (char*)Plds;
    for (int ch = tid; ch < 2352; ch += 256) {
        int row = ch / 12, seg = ch - row * 12;
        int addr = (row * 192 + seg * 16) ^ ((row & 7) << 4);
        *(uint4v*)(pb + addr) = *(const uint4v*)(P + ch * 8);
    }
    int rofs[13], rx[13];
    #pragma unroll
    for (int nt = 0; nt < 13; nt++) {
        int r = nt * 16 + m; if (r > 195) r = 195;
        rofs[nt] = r * 192 + quad * 16;
        rx[nt]   = (r & 7) << 4;
    }
    __syncthreads();

    for (int bi = 0; bi < 8; bi++) {
        const bf16* T = Tt + (size_t)(bg * 8 + bi) * (128 * 96);
        f32x4 acc[2][13] = {};
        #pragma unroll
        for (int kk = 0; kk < 96; kk += 32) {
            bf16x8 a0 = *(const bf16x8*)(T + (size_t)(w * 32 + m) * 96 + kk + quad * 8);
            bf16x8 a1 = *(const bf16x8*)(T + (size_t)(w * 32 + 16 + m) * 96 + kk + quad * 8);
            #pragma unroll
            for (int nt = 0; nt < 13; nt++) {
                bf16x8 bb = *(const bf16x8*)(pb + ((rofs[nt] + kk * 2) ^ rx[nt]));
                acc[0][nt] = MFMA16(a0, bb, acc[0][nt]);
                acc[1][nt] = MFMA16(a1, bb, acc[1][nt]);
            }
        }
        float mx = -3.4e38f;
        #pragma unroll
        for (int mt = 0; mt < 2; mt++)
            #pragma unroll
            for (int nt = 0; nt < 13; nt++)
                #pragma unroll
                for (int r = 0; r < 4; r++) mx = fmaxf(mx, acc[mt][nt][r]);
        #pragma unroll
        for (int dd = 1; dd < 64; dd <<= 1) mx = fmaxf(mx, __shfl_xor(mx, dd));
        if (lane == 0) red[bi][w] = mx;
    }
    __syncthreads();

    // fused epilogue: wave w handles bi = w and bi = w+4
    #pragma unroll
    for (int half = 0; half < 2; half++) {
        int bi = w + half * 4;
        int i  = bg * 8 + bi;          // b row
        int pr = i * 64 + c;
        float scll = fmaxf(fmaxf(red[bi][0], red[bi][1]), fmaxf(red[bi][2], red[bi][3]));
        bool act = lane < 48;
        float c0 = 0, c1 = 0, t0 = 0, t1 = 0;
        float dj0 = 0, dj1 = 0, di0 = 0, di1 = 0, v0 = 0, v1 = 0, g0 = 0, g1 = 0, bb0 = 0, bb1 = 0;
        if (act) {
            f32x2 cc  = *(const f32x2*)(Ctx + (size_t)pr * 96 + lane * 2);
            f32x2 tt  = *(const f32x2*)(t + i * 96 + lane * 2);
            f32x2 ddj = *(const f32x2*)(d + c * 96 + lane * 2);
            f32x2 ddi = *(const f32x2*)(d + i * 96 + lane * 2);
            f32x2 vv  = *(const f32x2*)(v + c * 96 + lane * 2);
            f32x2 gg  = *(const f32x2*)(ln_g + lane * 2);
            f32x2 bbv = *(const f32x2*)(ln_b + lane * 2);
            c0 = cc[0]; c1 = cc[1]; t0 = tt[0]; t1 = tt[1];
            dj0 = ddj[0]; dj1 = ddj[1]; di0 = ddi[0]; di1 = ddi[1];
            v0 = vv[0]; v1 = vv[1];
            g0 = gg[0]; g1 = gg[1]; bb0 = bbv[0]; bb1 = bbv[1];
        }
        float s = c0 + c1;
        #pragma unroll
        for (int k = 1; k < 64; k <<= 1) s += __shfl_xor(s, k);
        float mean = s * (1.0f / 96.0f);
        float e0 = act ? (c0 - mean) : 0.0f;
        float e1 = act ? (c1 - mean) : 0.0f;
        float q = e0 * e0 + e1 * e1;
        #pragma unroll
        for (int k = 1; k < 64; k <<= 1) q += __shfl_xor(q, k);
        float rstd = rsqrtf(q * (1.0f / 96.0f) + 1e-5f);
        float y0 = act ? (e0 * rstd * g0 + bb0) : 0.0f;
        float y1 = act ? (e1 * rstd * g1 + bb1) : 0.0f;
        float dot = y0 * di0 + y1 * di1;   // S_TGL uses d_i
        float ssq = y0 * y0 + y1 * y1;
        float tg  = t0 * dj0 + t1 * dj1;   // S_TGG uses d_j
        float cg  = t0 * v0 + t1 * v1;
        #pragma unroll
        for (int k = 1; k < 64; k <<= 1) {
            dot += __shfl_xor(dot, k); ssq += __shfl_xor(ssq, k);
            tg  += __shfl_xor(tg, k);  cg  += __shfl_xor(cg, k);
        }
        if (lane == 0) {
            float stgl = dot / fmaxf(sqrtf(ssq), 1e-6f);
            out[pr] = 0.5f * (tg + stgl) + 0.5f * (cg + scll);
        }
    }
}

// ---------------- launch ----------------

extern "C" void kernel_launch(void* const* d_in, const int* in_sizes, int n_in,
                              void* d_out, int out_size, void* d_ws, size_t ws_size,
                              hipStream_t stream)
{
    (void)in_sizes; (void)n_in; (void)out_size; (void)ws_size;
    char* ws = (char*)d_ws;
    float* t     = (float*)(ws + 0);               // 64*96 f32
    float* d     = (float*)(ws + 24576);
    float* v     = (float*)(ws + 49152);
    bf16* Wb = (bf16*)(ws + 106496);               // 8*96*512 bf16
    bf16* Qb = (bf16*)(ws + 892928);               // 8192*96 bf16
    bf16* Kb = (bf16*)(ws + 892928 + 1572864);
    bf16* Vb = (bf16*)(ws + 892928 + 2 * 1572864);
    bf16* Tt = (bf16*)(ws + 892928 + 3 * 1572864);
    bf16* Vp = (bf16*)(ws + 892928 + 4 * 1572864);         // 12544*96 bf16
    float* Ctx = (float*)(ws + 892928 + 4 * 1572864 + 2408448); // 4096*96 f32

    WPtrs wp;
    wp.W[0] = (const float*)d_in[6];   // W_t_cls
    wp.W[1] = (const float*)d_in[8];   // W_d_cls
    wp.W[2] = (const float*)d_in[10];  // W_v_cls
    wp.W[3] = (const float*)d_in[16];  // W_tgl_q
    wp.W[4] = (const float*)d_in[18];  // W_tgl_k
    wp.W[5] = (const float*)d_in[20];  // W_tgl_v
    wp.W[6] = (const float*)d_in[12];  // W_t_tok
    wp.W[7] = (const float*)d_in[14];  // W_v_patch
    hipLaunchKernelGGL(cvtw_kernel, dim3(384), dim3(256), 0, stream, wp, Wb);

    ProjParams pp;
    pp.Wb = Wb;
    pp.src[0] = (const float*)d_in[2];  pp.B[0] = (const float*)d_in[7];  pp.dst[0] = t;   // t_cls
    pp.src[1] = (const float*)d_in[0];  pp.B[1] = (const float*)d_in[9];  pp.dst[1] = d;   // d_cls
    pp.src[2] = (const float*)d_in[4];  pp.B[2] = (const float*)d_in[11]; pp.dst[2] = v;   // v_cls
    pp.src[3] = (const float*)d_in[1];  pp.B[3] = (const float*)d_in[17]; pp.dst[3] = Qb;  // Q (scaled)
    pp.src[4] = (const float*)d_in[3];  pp.B[4] = (const float*)d_in[19]; pp.dst[4] = Kb;  // K
    pp.src[5] = (const float*)d_in[3];  pp.B[5] = (const float*)d_in[21]; pp.dst[5] = Vb;  // V
    pp.src[6] = (const float*)d_in[3];  pp.B[6] = (const float*)d_in[13]; pp.dst[6] = Tt;  // t_tok
    pp.src[7] = (const float*)d_in[5];  pp.B[7] = (const float*)d_in[15]; pp.dst[7] = Vp;  // v_patch
    hipLaunchKernelGGL(proj_kernel, dim3(356), dim3(256), 0, stream, pp);

    hipLaunchKernelGGL(attn_kernel, dim3(4096), dim3(256), 0, stream,
                       (const bf16*)Qb, (const bf16*)Kb, (const bf16*)Vb, Ctx);
    hipLaunchKernelGGL(cll_kernel, dim3(512), dim3(256), 0, stream,
                       (const bf16*)Tt, (const bf16*)Vp,
                       (const float*)Ctx, (const float*)t, (const float*)d, (const float*)v,
                       (const float*)d_in[22], (const float*)d_in[23], (float*)d_out);
}